// Round 4
// baseline (185.806 us; speedup 1.0000x reference)
//
#include <hip/hip_runtime.h>
#include <hip/hip_bf16.h>

// ---------------------------------------------------------------------------
// GlobalIntrinsicLinear: Fastfood update + GEMM
//   LL = 1<<20, DD = 1024*768, OUT=1024, IN=768, M = 8*2048 = 16384
// Inputs: x(8,2048,768) f32, theta(2048) f32, W_0(1024,768) f32, b(1024) f32,
//         BB(LL) f32, GG(LL) f32, Pi(LL) int32 (harness narrows int64)
// Output: (8,2048,1024) f32
//
// R11: (1) x->bf16 precast kernel REMOVED: k7 reads x f32 and converts during
//      A staging (global->reg at iter top, cvt_pk+ds_write at iter bottom,
//      double-buffered; T14 pattern). Grid swapped to n-major dim3(8,128) so
//      the 8 n-blocks sharing an A-panel dispatch consecutively -> panel
//      fetched from HBM once (R8's FETCH blowup was m-major dispatch).
//      Net: -50 MB HBM, one fewer kernel.
//      (2) k0 folded into k3 as redundant per-block in-reg r01 FWHT
//      (6 shfl stages + two 4-partner LDS rounds) - kills a serialized
//      1-block launch and the r01g round-trip.
// ---------------------------------------------------------------------------

#define LL (1 << 20)
#define DD (1024 * 768)
#define OUTF 1024
#define INF 768
#define MROWS 16384

typedef __attribute__((ext_vector_type(8))) short s16x8;
typedef __attribute__((ext_vector_type(4))) float f32x4;
typedef __attribute__((ext_vector_type(16))) float f32x16;

__device__ __forceinline__ unsigned short f2bf(float f) {
    union { float f; unsigned u; } v; v.f = f;
    unsigned r = v.u + 0x7FFF + ((v.u >> 16) & 1);   // RNE
    return (unsigned short)(r >> 16);
}

// packed f32->bf16 RNE; no builtin on gfx950 (m240)
__device__ __forceinline__ unsigned cvt_pk_bf16(float lo, float hi) {
    unsigned r;
    asm("v_cvt_pk_bf16_f32 %0, %1, %2" : "=v"(r) : "v"(lo), "v"(hi));
    return r;
}

// ---------------------------------------------------------------------------
// K3: {in-block r01 FWHT} + gather (Pi,GG) + lo-FWHT-1024 per hi-row + GG^2
// partials. 256 blocks x 1024 threads; block b handles hi-rows 4b..4b+3
// (sub-block s_r = t>>8, tt = t&255 owns lo = 4tt..4tt+3).
// r01: thread t owns el t (row0) and t+1024 (row1) of BB*theta; FWHT-1024
// bits 0-5 via shfl, bits 6-7 / 8-9 via two 4-partner LDS rounds.
// Gather FWHT bits: 0-1 in-reg, 2-7 lane shfl, 8-9 one 4-partner LDS round.
// Output T2 in [lo4][hi] float4-blocked layout via LDS transpose.
// ---------------------------------------------------------------------------
__global__ __launch_bounds__(1024)
void k3_gather_fwht_lo(const int* __restrict__ Pi, const float* __restrict__ GG,
                       const float* __restrict__ BB, const float* __restrict__ theta,
                       f32x4* __restrict__ T2, float* __restrict__ partial) {
    __shared__ float r01s[2048];
    __shared__ f32x4 sA[1024];       // 16 KB
    __shared__ float sB[4 * 1028];   // 16.4 KB (pitch 1028 breaks conflicts)
    __shared__ float ws[16];
    const int t = threadIdx.x;
    const int s_r = t >> 8, tt = t & 255, lane = t & 63;
    const int row = blockIdx.x * 4 + s_r;

    // gather operands early (latency hidden behind r01 work)
    const int4   pv = ((const int4*)Pi)[row * 256 + tt];
    const float4 gv = ((const float4*)GG)[row * 256 + tt];

    // ---- r01 (redundant per block): FWHT-1024 of the two nonzero rows ----
    float w0 = BB[t] * theta[t];
    float w1 = BB[t + 1024] * theta[t + 1024];
    #pragma unroll
    for (int j = 0; j < 6; j++) {
        const float sgn = ((lane >> j) & 1) ? -1.0f : 1.0f;
        float o0 = __shfl_xor(w0, 1 << j, 64);
        float o1 = __shfl_xor(w1, 1 << j, 64);
        w0 = fmaf(sgn, w0, o0);
        w1 = fmaf(sgn, w1, o1);
    }
    float2* sr = (float2*)sB;        // 8 KB scratch (sB reused later)
    sr[t] = make_float2(w0, w1);
    __syncthreads();
    {   // bits 6-7
        const int b = t & ~192;
        const float2 q00 = sr[b], q10 = sr[b + 64], q01 = sr[b + 128], q11 = sr[b + 192];
        const float s6 = (t & 64) ? -1.0f : 1.0f;
        const float s7 = (t & 128) ? -1.0f : 1.0f;
        w0 = (q00.x + s7 * q01.x) + s6 * (q10.x + s7 * q11.x);
        w1 = (q00.y + s7 * q01.y) + s6 * (q10.y + s7 * q11.y);
    }
    __syncthreads();
    sr[t] = make_float2(w0, w1);
    // GG^2 block partial (placed here to overlap the barrier)
    float g2 = gv.x * gv.x + gv.y * gv.y + gv.z * gv.z + gv.w * gv.w;
    #pragma unroll
    for (int o = 32; o > 0; o >>= 1) g2 += __shfl_down(g2, o, 64);
    if (lane == 0) ws[t >> 6] = g2;
    __syncthreads();
    {   // bits 8-9
        const int b = t & ~768;
        const float2 q00 = sr[b], q10 = sr[b + 256], q01 = sr[b + 512], q11 = sr[b + 768];
        const float s8 = (t & 256) ? -1.0f : 1.0f;
        const float s9 = (t & 512) ? -1.0f : 1.0f;
        w0 = (q00.x + s9 * q01.x) + s8 * (q10.x + s9 * q11.x);
        w1 = (q00.y + s9 * q01.y) + s8 * (q10.y + s9 * q11.y);
    }
    r01s[t] = w0;
    r01s[1024 + t] = w1;
    __syncthreads();   // r01s ready (ws too); sr/sB free again

    // ---- gather + lo-FWHT ----
    float v[4];
    {
        int p; float g;
        p = pv.x; g = gv.x;
        v[0] = (r01s[p & 1023] + (((p >> 10) & 1) ? -1.0f : 1.0f) * r01s[1024 + (p & 1023)]) * g;
        p = pv.y; g = gv.y;
        v[1] = (r01s[p & 1023] + (((p >> 10) & 1) ? -1.0f : 1.0f) * r01s[1024 + (p & 1023)]) * g;
        p = pv.z; g = gv.z;
        v[2] = (r01s[p & 1023] + (((p >> 10) & 1) ? -1.0f : 1.0f) * r01s[1024 + (p & 1023)]) * g;
        p = pv.w; g = gv.w;
        v[3] = (r01s[p & 1023] + (((p >> 10) & 1) ? -1.0f : 1.0f) * r01s[1024 + (p & 1023)]) * g;
    }
    float a;
    a = v[0]; v[0] = a + v[1]; v[1] = a - v[1];
    a = v[2]; v[2] = a + v[3]; v[3] = a - v[3];
    a = v[0]; v[0] = a + v[2]; v[2] = a - v[2];
    a = v[1]; v[1] = a + v[3]; v[3] = a - v[3];
    #pragma unroll
    for (int j = 0; j < 6; j++) {
        const float sgn = ((lane >> j) & 1) ? -1.0f : 1.0f;
        #pragma unroll
        for (int c = 0; c < 4; c++) {
            float o = __shfl_xor(v[c], 1 << j, 64);
            v[c] = fmaf(sgn, v[c], o);
        }
    }
    {
        f32x4 vv; vv.x = v[0]; vv.y = v[1]; vv.z = v[2]; vv.w = v[3];
        sA[t] = vv;
    }
    __syncthreads();
    {
        const int b = t & ~192;
        const f32x4 q00 = sA[b];
        const f32x4 q10 = sA[b + 64];
        const f32x4 q01 = sA[b + 128];
        const f32x4 q11 = sA[b + 192];
        const float s8 = (tt & 64) ? -1.0f : 1.0f;
        const float s9 = (tt & 128) ? -1.0f : 1.0f;
        #pragma unroll
        for (int c = 0; c < 4; c++)
            v[c] = (q00[c] + s9 * q01[c]) + s8 * (q10[c] + s9 * q11[c]);
    }
    if (t == 0) {
        float s = 0;
        #pragma unroll
        for (int i = 0; i < 16; i++) s += ws[i];
        partial[blockIdx.x] = s;
    }
    {
        f32x4 vv; vv.x = v[0]; vv.y = v[1]; vv.z = v[2]; vv.w = v[3];
        *(f32x4*)&sB[s_r * 1028 + 4 * tt] = vv;
    }
    __syncthreads();
    {
        const int rl = t & 3;          // row_local
        const int lo4 = t >> 2;        // 0..255
        const f32x4 w = *(const f32x4*)&sB[rl * 1028 + lo4 * 4];
        T2[(size_t)lo4 * 1024 + blockIdx.x * 4 + rl] = w;
    }
}

// ---------------------------------------------------------------------------
// K4: hi-FWHT-1024 per lo-column + W_eff epilogue.
// 256 blocks x 1024 threads; block g owns lo = 4g..4g+3 (one float4/thread,
// hi = t). Reads T2[g*1024 + t]: 16 KB contiguous. FWHT bits 0-5 via shfl,
// bits 6-7 and 8-9 via two LDS rounds (4-partner combine). 3 barriers total.
// ---------------------------------------------------------------------------
__global__ __launch_bounds__(1024)
void k4_fwht_hi(const f32x4* __restrict__ T2, const float* __restrict__ partial,
                const float* __restrict__ W0, ushort* __restrict__ WB) {
    __shared__ f32x4 sx[1024];   // 16 KB
    __shared__ float rw[17];
    const int t = threadIdx.x;
    const int g = blockIdx.x;
    const int lane = t & 63;

    float pr = 0.0f;
    if (t < 256) pr = partial[t];
    #pragma unroll
    for (int o = 32; o > 0; o >>= 1) pr += __shfl_down(pr, o, 64);
    if (t < 256 && lane == 0) rw[t >> 6] = pr;

    f32x4 vv = T2[(size_t)g * 1024 + t];
    #pragma unroll
    for (int j = 0; j < 6; j++) {
        const float sgn = ((lane >> j) & 1) ? -1.0f : 1.0f;
        #pragma unroll
        for (int c = 0; c < 4; c++) {
            float o = __shfl_xor(vv[c], 1 << j, 64);
            vv[c] = fmaf(sgn, vv[c], o);
        }
    }
    sx[t] = vv;
    __syncthreads();   // sx + rw[0..3] ready
    if (t == 0) rw[16] = rw[0] + rw[1] + rw[2] + rw[3];
    {
        const int b = t & ~192;
        const f32x4 q00 = sx[b];
        const f32x4 q10 = sx[b + 64];
        const f32x4 q01 = sx[b + 128];
        const f32x4 q11 = sx[b + 192];
        const float s6 = (t & 64) ? -1.0f : 1.0f;
        const float s7 = (t & 128) ? -1.0f : 1.0f;
        #pragma unroll
        for (int c = 0; c < 4; c++)
            vv[c] = (q00[c] + s7 * q01[c]) + s6 * (q10[c] + s7 * q11[c]);
    }
    __syncthreads();   // protect sx overwrite; publishes rw[16]
    sx[t] = vv;
    __syncthreads();
    {
        const int b = t & ~768;
        const f32x4 q00 = sx[b];
        const f32x4 q10 = sx[b + 256];
        const f32x4 q01 = sx[b + 512];
        const f32x4 q11 = sx[b + 768];
        const float s8 = (t & 256) ? -1.0f : 1.0f;
        const float s9 = (t & 512) ? -1.0f : 1.0f;
        #pragma unroll
        for (int c = 0; c < 4; c++)
            vv[c] = (q00[c] + s9 * q01[c]) + s8 * (q10[c] + s9 * q11[c]);
    }
    if (t < 768) {
        const float scale = rsqrtf(rw[16] * (float)DD);
        const size_t d = (size_t)t * 1024 + 4 * g;
        const float4 w = *(const float4*)&W0[d];
        ushort4 o;
        o.x = f2bf(w.x + vv.x * scale);
        o.y = f2bf(w.y + vv.y * scale);
        o.z = f2bf(w.z + vv.z * scale);
        o.w = f2bf(w.w + vv.w * scale);
        *(ushort4*)&WB[d] = o;
    }
}

// ---------------------------------------------------------------------------
// K7: GEMM  C[m][n] = sum_k A[m][k]*B[n][k] + bias[n]
// A: x (MROWS x 768 f32) converted to bf16 in-staging; B: 1024x768 bf16.
// Grid dim3(8,128) n-major: the 8 n-blocks of an A-panel dispatch
// consecutively -> panel fetched from HBM once, L2/L3 serve the rest.
// 128x128 tile, BK=64, 4 waves (2x2), 2x2 MFMA 32x32x16 per wave, dbuf:
//   iter t: {loadA(t+1)->regs, stageB(t+1)->LDS[nxt]}; MFMA on LDS[cur];
//           {cvt+ds_write A(t+1)->LDS[nxt]}; barrier (vm+lgkm drain).
// A's global latency hides under the MFMA phase; ds_write targets the
// buffer nobody reads this iter (WAR-safe via prev barrier).
// XOR-swizzled LDS: 16B slot s <-> row = s>>3, kc = (s&7) ^ (row&7).
// C/D: col = lane&31, row = (reg&3) + 8*(reg>>2) + 4*(lane>>5)  [m74/m101].
// ---------------------------------------------------------------------------
#define BM 128
#define BN 128
#define BK 64
#define KITERS (INF / BK)   // 12

__global__ __launch_bounds__(256)
void k7_gemm(const float* __restrict__ A, const ushort* __restrict__ B,
             const float* __restrict__ bias, float* __restrict__ C) {
    __shared__ ushort As[2][BM * BK];   // 2 x 16 KB
    __shared__ ushort Bs[2][BN * BK];   // 2 x 16 KB
    const int tid  = threadIdx.x;
    const int lane = tid & 63;
    const int wave = tid >> 6;
    const int n0 = blockIdx.x * BN;     // n-major grid
    const int m0 = blockIdx.y * BM;
    const int wm = (wave & 1) * 64;
    const int wn = (wave >> 1) * 64;

    const int fr_row = lane & 31;     // row within 32-tile
    const int fr_kh  = lane >> 5;     // k-half 0..1 (8 k each)

    f32x16 acc[2][2];
    #pragma unroll
    for (int i = 0; i < 2; i++)
        #pragma unroll
        for (int j = 0; j < 2; j++) acc[i][j] = (f32x16)(0.0f);

    // per-thread A slot geometry (constant across kt): slot s = j*256+tid
    int arow[4], akc[4];
    #pragma unroll
    for (int j = 0; j < 4; j++) {
        const int s = j * 256 + tid;
        arow[j] = s >> 3;
        akc[j]  = (s & 7) ^ (arow[j] & 7);
    }

    // load A k-tile kt (f32) into regs; 8 coalesced 16B loads
    f32x4 ar[8];
    auto loadA = [&](int kt) {
        #pragma unroll
        for (int j = 0; j < 4; j++) {
            const float* ga = A + (size_t)(m0 + arow[j]) * INF + kt + akc[j] * 8;
            ar[2 * j]     = *(const f32x4*)ga;
            ar[2 * j + 1] = *(const f32x4*)(ga + 4);
        }
    };
    // cvt + linear ds_write_b128 into buffer bsel (slots pre-swizzled via akc)
    auto writeA = [&](int bsel) {
        #pragma unroll
        for (int j = 0; j < 4; j++) {
            union { s16x8 v; unsigned u[4]; } o;
            const f32x4 lo = ar[2 * j], hi = ar[2 * j + 1];
            o.u[0] = cvt_pk_bf16(lo.x, lo.y);
            o.u[1] = cvt_pk_bf16(lo.z, lo.w);
            o.u[2] = cvt_pk_bf16(hi.x, hi.y);
            o.u[3] = cvt_pk_bf16(hi.z, hi.w);
            *(s16x8*)&As[bsel][(j * 256 + tid) * 8] = o.v;
        }
    };
    // stage B k-tile kt into buffer bsel (4 global_load_lds, 16B each)
    auto stageB = [&](int bsel, int kt) {
        #pragma unroll
        for (int i = 0; i < 4; i++) {
            const int s   = i * 256 + tid;
            const int row = s >> 3;
            const int kc  = (s & 7) ^ (row & 7);
            const ushort* gb = B + (size_t)(n0 + row) * INF + kt + kc * 8;
            __builtin_amdgcn_global_load_lds(
                (const __attribute__((address_space(1))) void*)gb,
                (__attribute__((address_space(3))) void*)&Bs[bsel][i * 2048 + wave * 512], 16, 0, 0);
        }
    };

    // prologue: tile 0
    loadA(0);
    stageB(0, 0);
    writeA(0);
    __syncthreads();                     // vm+lgkm drain: tile 0 ready

    for (int t = 0; t < KITERS; t++) {
        const int cur = t & 1;
        const bool pf = (t + 1 < KITERS);
        if (pf) {
            loadA((t + 1) * BK);         // global f32 -> regs (hidden under MFMA)
            stageB(cur ^ 1, (t + 1) * BK);
        }

        const ushort* Ab = As[cur];
        const ushort* Bb = Bs[cur];
        #pragma unroll
        for (int ks = 0; ks < 4; ks++) {
            const int kc = ks * 2 + fr_kh;       // 8-ushort unit within BK
            s16x8 af[2], bf[2];
            #pragma unroll
            for (int mi = 0; mi < 2; mi++) {
                const int r = wm + mi * 32 + fr_row;
                af[mi] = *(const s16x8*)&Ab[(r * 8 + (kc ^ (r & 7))) * 8];
            }
            #pragma unroll
            for (int ni = 0; ni < 2; ni++) {
                const int r = wn + ni * 32 + fr_row;
                bf[ni] = *(const s16x8*)&Bb[(r * 8 + (kc ^ (r & 7))) * 8];
            }
            #pragma unroll
            for (int mi = 0; mi < 2; mi++)
                #pragma unroll
                for (int ni = 0; ni < 2; ni++)
                    acc[mi][ni] = __builtin_amdgcn_mfma_f32_32x32x16_bf16(
                        af[mi], bf[ni], acc[mi][ni], 0, 0, 0);
        }
        if (pf) writeA(cur ^ 1);         // WAR-safe: prev barrier cleared readers
        // barrier: all waves done with buf[cur]; auto vmcnt(0)/lgkmcnt(0)
        // drain completes B tile t+1 and A ds_writes.
        __syncthreads();
    }

    // --- epilogue: C/D col=lane&31, row=(reg&3)+8*(reg>>2)+4*(lane>>5) ---
    const int ccol = lane & 31;
    const int rbase = (lane >> 5) * 4;
    #pragma unroll
    for (int ni = 0; ni < 2; ni++) {
        const int n = n0 + wn + ni * 32 + ccol;
        const float bv = bias[n];
        #pragma unroll
        for (int mi = 0; mi < 2; mi++) {
            const int mb = m0 + wm + mi * 32 + rbase;
            #pragma unroll
            for (int r = 0; r < 16; r++) {
                const int m = mb + (r & 3) + 8 * (r >> 2);
                C[(size_t)m * OUTF + n] = acc[mi][ni][r] + bv;
            }
        }
    }
}

// ---------------------------------------------------------------------------
extern "C" void kernel_launch(void* const* d_in, const int* in_sizes, int n_in,
                              void* d_out, int out_size, void* d_ws, size_t ws_size,
                              hipStream_t stream) {
    (void)in_sizes; (void)n_in; (void)out_size; (void)ws_size;
    const float* x     = (const float*)d_in[0];
    const float* theta = (const float*)d_in[1];
    const float* W0    = (const float*)d_in[2];
    const float* bias  = (const float*)d_in[3];
    const float* BB    = (const float*)d_in[4];
    const float* GG    = (const float*)d_in[5];
    const int*   Pi    = (const int*)d_in[6];      // int64 inputs arrive as int32
    float* out = (float*)d_out;

    char* ws = (char*)d_ws;
    f32x4*  T2   = (f32x4*)ws;                       // LL f32 = 4194304 B
    ushort* WB   = (ushort*)(ws + 4194304);          // 1024*768 bf16 = 1572864 B
    float*  PART = (float*)(ws + 5767168);           // 256 f32 partials

    k3_gather_fwht_lo<<<256, 1024, 0, stream>>>(Pi, GG, BB, theta, T2, PART);
    k4_fwht_hi      <<<256, 1024, 0, stream>>>(T2, PART, W0, WB);
    k7_gemm<<<dim3(OUTF/BN, MROWS/BM), 256, 0, stream>>>(x, WB, bias, out);
}

// Round 5
// 178.164 us; speedup vs baseline: 1.0429x; 1.0429x over previous
//
#include <hip/hip_runtime.h>
#include <hip/hip_bf16.h>

// ---------------------------------------------------------------------------
// GlobalIntrinsicLinear: Fastfood update + GEMM
//   LL = 1<<20, DD = 1024*768, OUT=1024, IN=768, M = 8*2048 = 16384
// Inputs: x(8,2048,768) f32, theta(2048) f32, W_0(1024,768) f32, b(1024) f32,
//         BB(LL) f32, GG(LL) f32, Pi(LL) int32 (harness narrows int64)
// Output: (8,2048,1024) f32
//
// R12: (1) k7 REVERTED to bf16-XB precast + global_load_lds + m-major grid
//      (R11's f32 fusion: FETCH 198MB from simultaneous cross-XCD misses).
//      (2) k7 BK 64->32: LDS 64->32 KB/block -> 5 blocks/CU co-resident
//      (was 2); barrier drains hide under other blocks' MFMA (m114).
//      (3) k01 launch killed: x->bf16 cast folded into k3/k4 as streaming
//      tails (half each); r01 FWHT stays in-block in k3 (R11-proven).
// ---------------------------------------------------------------------------

#define LL (1 << 20)
#define DD (1024 * 768)
#define OUTF 1024
#define INF 768
#define MROWS 16384

typedef __attribute__((ext_vector_type(8))) short s16x8;
typedef __attribute__((ext_vector_type(4))) float f32x4;
typedef __attribute__((ext_vector_type(16))) float f32x16;

__device__ __forceinline__ unsigned short f2bf(float f) {
    union { float f; unsigned u; } v; v.f = f;
    unsigned r = v.u + 0x7FFF + ((v.u >> 16) & 1);   // RNE
    return (unsigned short)(r >> 16);
}

// packed f32->bf16 RNE; no builtin on gfx950 (m240)
__device__ __forceinline__ unsigned cvt_pk_bf16(float lo, float hi) {
    unsigned r;
    asm("v_cvt_pk_bf16_f32 %0, %1, %2" : "=v"(r) : "v"(lo), "v"(hi));
    return r;
}

// ---------------------------------------------------------------------------
// K3: {in-block r01 FWHT} + gather (Pi,GG) + lo-FWHT-1024 per hi-row + GG^2
// partials + {x-cast tail, first half}. 256 blocks x 1024 threads.
// Block b handles hi-rows 4b..4b+3 (sub-block s_r = t>>8, tt = t&255 owns
// lo = 4tt..4tt+3).
// r01: thread t owns el t (row0) and t+1024 (row1) of BB*theta; FWHT-1024
// bits 0-5 via shfl, bits 6-7 / 8-9 via two 4-partner LDS rounds.
// Gather FWHT bits: 0-1 in-reg, 2-7 lane shfl, 8-9 one 4-partner LDS round.
// Output T2 in [lo4][hi] float4-blocked layout via LDS transpose.
// ---------------------------------------------------------------------------
__global__ __launch_bounds__(1024)
void k3_gather_fwht_lo(const int* __restrict__ Pi, const float* __restrict__ GG,
                       const float* __restrict__ BB, const float* __restrict__ theta,
                       const float* __restrict__ X, ushort* __restrict__ XB,
                       f32x4* __restrict__ T2, float* __restrict__ partial) {
    __shared__ float r01s[2048];
    __shared__ f32x4 sA[1024];       // 16 KB
    __shared__ float sB[4 * 1028];   // 16.4 KB (pitch 1028 breaks conflicts)
    __shared__ float ws[16];
    const int t = threadIdx.x;
    const int s_r = t >> 8, tt = t & 255, lane = t & 63;
    const int row = blockIdx.x * 4 + s_r;

    // gather operands early (latency hidden behind r01 work)
    const int4   pv = ((const int4*)Pi)[row * 256 + tt];
    const float4 gv = ((const float4*)GG)[row * 256 + tt];

    // ---- r01 (redundant per block): FWHT-1024 of the two nonzero rows ----
    float w0 = BB[t] * theta[t];
    float w1 = BB[t + 1024] * theta[t + 1024];
    #pragma unroll
    for (int j = 0; j < 6; j++) {
        const float sgn = ((lane >> j) & 1) ? -1.0f : 1.0f;
        float o0 = __shfl_xor(w0, 1 << j, 64);
        float o1 = __shfl_xor(w1, 1 << j, 64);
        w0 = fmaf(sgn, w0, o0);
        w1 = fmaf(sgn, w1, o1);
    }
    float2* sr = (float2*)sB;        // 8 KB scratch (sB reused later)
    sr[t] = make_float2(w0, w1);
    __syncthreads();
    {   // bits 6-7
        const int b = t & ~192;
        const float2 q00 = sr[b], q10 = sr[b + 64], q01 = sr[b + 128], q11 = sr[b + 192];
        const float s6 = (t & 64) ? -1.0f : 1.0f;
        const float s7 = (t & 128) ? -1.0f : 1.0f;
        w0 = (q00.x + s7 * q01.x) + s6 * (q10.x + s7 * q11.x);
        w1 = (q00.y + s7 * q01.y) + s6 * (q10.y + s7 * q11.y);
    }
    __syncthreads();
    sr[t] = make_float2(w0, w1);
    // GG^2 block partial (placed here to overlap the barrier)
    float g2 = gv.x * gv.x + gv.y * gv.y + gv.z * gv.z + gv.w * gv.w;
    #pragma unroll
    for (int o = 32; o > 0; o >>= 1) g2 += __shfl_down(g2, o, 64);
    if (lane == 0) ws[t >> 6] = g2;
    __syncthreads();
    {   // bits 8-9
        const int b = t & ~768;
        const float2 q00 = sr[b], q10 = sr[b + 256], q01 = sr[b + 512], q11 = sr[b + 768];
        const float s8 = (t & 256) ? -1.0f : 1.0f;
        const float s9 = (t & 512) ? -1.0f : 1.0f;
        w0 = (q00.x + s9 * q01.x) + s8 * (q10.x + s9 * q11.x);
        w1 = (q00.y + s9 * q01.y) + s8 * (q10.y + s9 * q11.y);
    }
    r01s[t] = w0;
    r01s[1024 + t] = w1;
    __syncthreads();   // r01s ready (ws too); sr/sB free again

    // ---- gather + lo-FWHT ----
    float v[4];
    {
        int p; float g;
        p = pv.x; g = gv.x;
        v[0] = (r01s[p & 1023] + (((p >> 10) & 1) ? -1.0f : 1.0f) * r01s[1024 + (p & 1023)]) * g;
        p = pv.y; g = gv.y;
        v[1] = (r01s[p & 1023] + (((p >> 10) & 1) ? -1.0f : 1.0f) * r01s[1024 + (p & 1023)]) * g;
        p = pv.z; g = gv.z;
        v[2] = (r01s[p & 1023] + (((p >> 10) & 1) ? -1.0f : 1.0f) * r01s[1024 + (p & 1023)]) * g;
        p = pv.w; g = gv.w;
        v[3] = (r01s[p & 1023] + (((p >> 10) & 1) ? -1.0f : 1.0f) * r01s[1024 + (p & 1023)]) * g;
    }
    float a;
    a = v[0]; v[0] = a + v[1]; v[1] = a - v[1];
    a = v[2]; v[2] = a + v[3]; v[3] = a - v[3];
    a = v[0]; v[0] = a + v[2]; v[2] = a - v[2];
    a = v[1]; v[1] = a + v[3]; v[3] = a - v[3];
    #pragma unroll
    for (int j = 0; j < 6; j++) {
        const float sgn = ((lane >> j) & 1) ? -1.0f : 1.0f;
        #pragma unroll
        for (int c = 0; c < 4; c++) {
            float o = __shfl_xor(v[c], 1 << j, 64);
            v[c] = fmaf(sgn, v[c], o);
        }
    }
    {
        f32x4 vv; vv.x = v[0]; vv.y = v[1]; vv.z = v[2]; vv.w = v[3];
        sA[t] = vv;
    }
    __syncthreads();
    {
        const int b = t & ~192;
        const f32x4 q00 = sA[b];
        const f32x4 q10 = sA[b + 64];
        const f32x4 q01 = sA[b + 128];
        const f32x4 q11 = sA[b + 192];
        const float s8 = (tt & 64) ? -1.0f : 1.0f;
        const float s9 = (tt & 128) ? -1.0f : 1.0f;
        #pragma unroll
        for (int c = 0; c < 4; c++)
            v[c] = (q00[c] + s9 * q01[c]) + s8 * (q10[c] + s9 * q11[c]);
    }
    if (t == 0) {
        float s = 0;
        #pragma unroll
        for (int i = 0; i < 16; i++) s += ws[i];
        partial[blockIdx.x] = s;
    }
    {
        f32x4 vv; vv.x = v[0]; vv.y = v[1]; vv.z = v[2]; vv.w = v[3];
        *(f32x4*)&sB[s_r * 1028 + 4 * tt] = vv;
    }
    __syncthreads();
    {
        const int rl = t & 3;          // row_local
        const int lo4 = t >> 2;        // 0..255
        const f32x4 w = *(const f32x4*)&sB[rl * 1028 + lo4 * 4];
        T2[(size_t)lo4 * 1024 + blockIdx.x * 4 + rl] = w;
    }

    // ---- x-cast tail: units 0..786431 (8 floats per unit), 3 per thread ----
    {
        const f32x4* X4 = (const f32x4*)X;
        s16x8* O = (s16x8*)XB;
        size_t u = (size_t)blockIdx.x * 3072 + t;
        #pragma unroll
        for (int j = 0; j < 3; j++, u += 1024) {
            const f32x4 A4 = X4[2 * u];
            const f32x4 B4 = X4[2 * u + 1];
            union { s16x8 v; unsigned w4[4]; } o;
            o.w4[0] = cvt_pk_bf16(A4.x, A4.y);
            o.w4[1] = cvt_pk_bf16(A4.z, A4.w);
            o.w4[2] = cvt_pk_bf16(B4.x, B4.y);
            o.w4[3] = cvt_pk_bf16(B4.z, B4.w);
            O[u] = o.v;
        }
    }
}

// ---------------------------------------------------------------------------
// K4: hi-FWHT-1024 per lo-column + W_eff epilogue + {x-cast tail, 2nd half}.
// 256 blocks x 1024 threads; block g owns lo = 4g..4g+3 (one float4/thread,
// hi = t). Reads T2[g*1024 + t]: 16 KB contiguous. FWHT bits 0-5 via shfl,
// bits 6-7 and 8-9 via two LDS rounds (4-partner combine). 3 barriers total.
// ---------------------------------------------------------------------------
__global__ __launch_bounds__(1024)
void k4_fwht_hi(const f32x4* __restrict__ T2, const float* __restrict__ partial,
                const float* __restrict__ W0, ushort* __restrict__ WB,
                const float* __restrict__ X, ushort* __restrict__ XB) {
    __shared__ f32x4 sx[1024];   // 16 KB
    __shared__ float rw[17];
    const int t = threadIdx.x;
    const int g = blockIdx.x;
    const int lane = t & 63;

    float pr = 0.0f;
    if (t < 256) pr = partial[t];
    #pragma unroll
    for (int o = 32; o > 0; o >>= 1) pr += __shfl_down(pr, o, 64);
    if (t < 256 && lane == 0) rw[t >> 6] = pr;

    f32x4 vv = T2[(size_t)g * 1024 + t];
    #pragma unroll
    for (int j = 0; j < 6; j++) {
        const float sgn = ((lane >> j) & 1) ? -1.0f : 1.0f;
        #pragma unroll
        for (int c = 0; c < 4; c++) {
            float o = __shfl_xor(vv[c], 1 << j, 64);
            vv[c] = fmaf(sgn, vv[c], o);
        }
    }
    sx[t] = vv;
    __syncthreads();   // sx + rw[0..3] ready
    if (t == 0) rw[16] = rw[0] + rw[1] + rw[2] + rw[3];
    {
        const int b = t & ~192;
        const f32x4 q00 = sx[b];
        const f32x4 q10 = sx[b + 64];
        const f32x4 q01 = sx[b + 128];
        const f32x4 q11 = sx[b + 192];
        const float s6 = (t & 64) ? -1.0f : 1.0f;
        const float s7 = (t & 128) ? -1.0f : 1.0f;
        #pragma unroll
        for (int c = 0; c < 4; c++)
            vv[c] = (q00[c] + s7 * q01[c]) + s6 * (q10[c] + s7 * q11[c]);
    }
    __syncthreads();   // protect sx overwrite; publishes rw[16]
    sx[t] = vv;
    __syncthreads();
    {
        const int b = t & ~768;
        const f32x4 q00 = sx[b];
        const f32x4 q10 = sx[b + 256];
        const f32x4 q01 = sx[b + 512];
        const f32x4 q11 = sx[b + 768];
        const float s8 = (t & 256) ? -1.0f : 1.0f;
        const float s9 = (t & 512) ? -1.0f : 1.0f;
        #pragma unroll
        for (int c = 0; c < 4; c++)
            vv[c] = (q00[c] + s9 * q01[c]) + s8 * (q10[c] + s9 * q11[c]);
    }
    if (t < 768) {
        const float scale = rsqrtf(rw[16] * (float)DD);
        const size_t d = (size_t)t * 1024 + 4 * g;
        const float4 w = *(const float4*)&W0[d];
        ushort4 o;
        o.x = f2bf(w.x + vv.x * scale);
        o.y = f2bf(w.y + vv.y * scale);
        o.z = f2bf(w.z + vv.z * scale);
        o.w = f2bf(w.w + vv.w * scale);
        *(ushort4*)&WB[d] = o;
    }

    // ---- x-cast tail: units 786432..1572863, 3 per thread ----
    {
        const f32x4* X4 = (const f32x4*)X;
        s16x8* O = (s16x8*)XB;
        size_t u = 786432 + (size_t)g * 3072 + t;
        #pragma unroll
        for (int j = 0; j < 3; j++, u += 1024) {
            const f32x4 A4 = X4[2 * u];
            const f32x4 B4 = X4[2 * u + 1];
            union { s16x8 v; unsigned w4[4]; } o;
            o.w4[0] = cvt_pk_bf16(A4.x, A4.y);
            o.w4[1] = cvt_pk_bf16(A4.z, A4.w);
            o.w4[2] = cvt_pk_bf16(B4.x, B4.y);
            o.w4[3] = cvt_pk_bf16(B4.z, B4.w);
            O[u] = o.v;
        }
    }
}

// ---------------------------------------------------------------------------
// K7: GEMM  C[m][n] = sum_k A[m][k]*B[n][k] + bias[n]
// A: MROWS x 768 bf16 (XB), B: 1024 x 768 bf16 (W_eff), C: f32.
// m-major grid dim3(128,8) (proven FETCH 30.8 MB: L3 holds bf16 A).
// 128x128 tile, BK=32, 4 waves (2x2), 2x2 MFMA 32x32x16 per wave, 2 k-steps.
// Double-buffered (T3 minimum): stage t+1 before compute t, 1 barrier/iter.
// LDS 32 KB/block -> 5 blocks/CU resident: drains overlap other blocks' MFMA.
// XOR-swizzled LDS: 16B slot s <-> row = s>>2, kc = (s&3) ^ (row&3)
// (8 lanes x 16B cover all 32 banks; residual aliasing is the free 2-way).
// C/D: col = lane&31, row = (reg&3) + 8*(reg>>2) + 4*(lane>>5)  [m74/m101].
// ---------------------------------------------------------------------------
#define BM 128
#define BN 128
#define BK 32
#define KITERS (INF / BK)   // 24

__global__ __launch_bounds__(256)
void k7_gemm(const ushort* __restrict__ A, const ushort* __restrict__ B,
             const float* __restrict__ bias, float* __restrict__ C) {
    __shared__ ushort As[2][BM * BK];   // 2 x 8 KB
    __shared__ ushort Bs[2][BN * BK];   // 2 x 8 KB
    const int tid  = threadIdx.x;
    const int lane = tid & 63;
    const int wave = tid >> 6;
    const int m0 = blockIdx.x * BM;
    const int n0 = blockIdx.y * BN;
    const int wm = (wave & 1) * 64;
    const int wn = (wave >> 1) * 64;

    const int fr_row = lane & 31;     // row within 32-tile
    const int fr_kh  = lane >> 5;     // k-half 0..1 (8 k each)

    f32x16 acc[2][2];
    #pragma unroll
    for (int i = 0; i < 2; i++)
        #pragma unroll
        for (int j = 0; j < 2; j++) acc[i][j] = (f32x16)(0.0f);

    // stage k-tile kt into buffer bsel (4 global_load_lds, 16B each)
    auto stage = [&](int bsel, int kt) {
        #pragma unroll
        for (int i = 0; i < 2; i++) {
            const int s   = i * 256 + tid;       // LDS slot 0..511 (16B units)
            const int row = s >> 2;              // 4 slots per row (BK=32)
            const int kc  = (s & 3) ^ (row & 3);
            const ushort* ga = A + (size_t)(m0 + row) * INF + kt + kc * 8;
            const ushort* gb = B + (size_t)(n0 + row) * INF + kt + kc * 8;
            __builtin_amdgcn_global_load_lds(
                (const __attribute__((address_space(1))) void*)ga,
                (__attribute__((address_space(3))) void*)&As[bsel][i * 2048 + wave * 512], 16, 0, 0);
            __builtin_amdgcn_global_load_lds(
                (const __attribute__((address_space(1))) void*)gb,
                (__attribute__((address_space(3))) void*)&Bs[bsel][i * 2048 + wave * 512], 16, 0, 0);
        }
    };

    stage(0, 0);
    __syncthreads();                     // drains vmcnt(0): tile 0 ready

    for (int t = 0; t < KITERS; t++) {
        const int cur = t & 1;
        if (t + 1 < KITERS) stage(cur ^ 1, (t + 1) * BK);   // prefetch next tile

        const ushort* Ab = As[cur];
        const ushort* Bb = Bs[cur];
        #pragma unroll
        for (int ks = 0; ks < 2; ks++) {
            const int kc = ks * 2 + fr_kh;       // 8-ushort unit within BK
            s16x8 af[2], bf[2];
            #pragma unroll
            for (int mi = 0; mi < 2; mi++) {
                const int r = wm + mi * 32 + fr_row;
                af[mi] = *(const s16x8*)&Ab[(r * 4 + (kc ^ (r & 3))) * 8];
            }
            #pragma unroll
            for (int ni = 0; ni < 2; ni++) {
                const int r = wn + ni * 32 + fr_row;
                bf[ni] = *(const s16x8*)&Bb[(r * 4 + (kc ^ (r & 3))) * 8];
            }
            #pragma unroll
            for (int mi = 0; mi < 2; mi++)
                #pragma unroll
                for (int ni = 0; ni < 2; ni++)
                    acc[mi][ni] = __builtin_amdgcn_mfma_f32_32x32x16_bf16(
                        af[mi], bf[ni], acc[mi][ni], 0, 0, 0);
        }
        // barrier: all waves done with buf[cur]; auto vmcnt drain completes
        // the prefetched tile. With 5 blocks/CU the stall overlaps others.
        __syncthreads();
    }

    // --- epilogue: C/D col=lane&31, row=(reg&3)+8*(reg>>2)+4*(lane>>5) ---
    const int ccol = lane & 31;
    const int rbase = (lane >> 5) * 4;
    #pragma unroll
    for (int ni = 0; ni < 2; ni++) {
        const int n = n0 + wn + ni * 32 + ccol;
        const float bv = bias[n];
        #pragma unroll
        for (int mi = 0; mi < 2; mi++) {
            const int mb = m0 + wm + mi * 32 + rbase;
            #pragma unroll
            for (int r = 0; r < 16; r++) {
                const int m = mb + (r & 3) + 8 * (r >> 2);
                C[(size_t)m * OUTF + n] = acc[mi][ni][r] + bv;
            }
        }
    }
}

// ---------------------------------------------------------------------------
extern "C" void kernel_launch(void* const* d_in, const int* in_sizes, int n_in,
                              void* d_out, int out_size, void* d_ws, size_t ws_size,
                              hipStream_t stream) {
    (void)in_sizes; (void)n_in; (void)out_size; (void)ws_size;
    const float* x     = (const float*)d_in[0];
    const float* theta = (const float*)d_in[1];
    const float* W0    = (const float*)d_in[2];
    const float* bias  = (const float*)d_in[3];
    const float* BB    = (const float*)d_in[4];
    const float* GG    = (const float*)d_in[5];
    const int*   Pi    = (const int*)d_in[6];      // int64 inputs arrive as int32
    float* out = (float*)d_out;

    char* ws = (char*)d_ws;
    ushort* XB   = (ushort*)ws;                      // 16384*768 bf16 = 25165824 B
    f32x4*  T2   = (f32x4*)(ws + 25165824);          // LL f32 = 4194304 B
    ushort* WB   = (ushort*)(ws + 29360128);         // 1024*768 bf16 = 1572864 B
    float*  PART = (float*)(ws + 30932992);          // 256 f32 partials

    k3_gather_fwht_lo<<<256, 1024, 0, stream>>>(Pi, GG, BB, theta, x, XB, T2, PART);
    k4_fwht_hi      <<<256, 1024, 0, stream>>>(T2, PART, W0, WB, x, XB);
    k7_gemm<<<dim3(MROWS/BM, OUTF/BN), 256, 0, stream>>>(XB, WB, bias, out);
}

// Round 6
// 162.098 us; speedup vs baseline: 1.1463x; 1.0991x over previous
//
#include <hip/hip_runtime.h>
#include <hip/hip_bf16.h>

// ---------------------------------------------------------------------------
// GlobalIntrinsicLinear: Fastfood update + GEMM
//   LL = 1<<20, DD = 1024*768, OUT=1024, IN=768, M = 8*2048 = 16384
// Inputs: x(8,2048,768) f32, theta(2048) f32, W_0(1024,768) f32, b(1024) f32,
//         BB(LL) f32, GG(LL) f32, Pi(LL) int32 (harness narrows int64)
// Output: (8,2048,1024) f32
//
// R13: consolidation of measured winners.
//   k7 = R10's BK=64 double-buffered global_load_lds GEMM (36us, conflicts
//        3.15M). R12's BK=32 variant REVERTED: 64B rows made the XOR swizzle
//        collide 8-way (bank start = 16r+4(r&3) mod 32 repeats every 4 rows;
//        conflicts 3.15M->9.4M, 57us). Swizzle requires 128B row pitch.
//   k3/k4 = R12's folded side-chain (in-block r01 + cast tails, ~13us total,
//        at the ~90MB BW floor). Side-chain is done.
// ---------------------------------------------------------------------------

#define LL (1 << 20)
#define DD (1024 * 768)
#define OUTF 1024
#define INF 768
#define MROWS 16384

typedef __attribute__((ext_vector_type(8))) short s16x8;
typedef __attribute__((ext_vector_type(4))) float f32x4;
typedef __attribute__((ext_vector_type(16))) float f32x16;

__device__ __forceinline__ unsigned short f2bf(float f) {
    union { float f; unsigned u; } v; v.f = f;
    unsigned r = v.u + 0x7FFF + ((v.u >> 16) & 1);   // RNE
    return (unsigned short)(r >> 16);
}

// packed f32->bf16 RNE; no builtin on gfx950 (m240)
__device__ __forceinline__ unsigned cvt_pk_bf16(float lo, float hi) {
    unsigned r;
    asm("v_cvt_pk_bf16_f32 %0, %1, %2" : "=v"(r) : "v"(lo), "v"(hi));
    return r;
}

// ---------------------------------------------------------------------------
// K3: {in-block r01 FWHT} + gather (Pi,GG) + lo-FWHT-1024 per hi-row + GG^2
// partials + {x-cast tail, first half}. 256 blocks x 1024 threads.
// Block b handles hi-rows 4b..4b+3 (sub-block s_r = t>>8, tt = t&255 owns
// lo = 4tt..4tt+3).
// r01: thread t owns el t (row0) and t+1024 (row1) of BB*theta; FWHT-1024
// bits 0-5 via shfl, bits 6-7 / 8-9 via two 4-partner LDS rounds.
// Gather FWHT bits: 0-1 in-reg, 2-7 lane shfl, 8-9 one 4-partner LDS round.
// Output T2 in [lo4][hi] float4-blocked layout via LDS transpose.
// ---------------------------------------------------------------------------
__global__ __launch_bounds__(1024)
void k3_gather_fwht_lo(const int* __restrict__ Pi, const float* __restrict__ GG,
                       const float* __restrict__ BB, const float* __restrict__ theta,
                       const float* __restrict__ X, ushort* __restrict__ XB,
                       f32x4* __restrict__ T2, float* __restrict__ partial) {
    __shared__ float r01s[2048];
    __shared__ f32x4 sA[1024];       // 16 KB
    __shared__ float sB[4 * 1028];   // 16.4 KB (pitch 1028 breaks conflicts)
    __shared__ float ws[16];
    const int t = threadIdx.x;
    const int s_r = t >> 8, tt = t & 255, lane = t & 63;
    const int row = blockIdx.x * 4 + s_r;

    // gather operands early (latency hidden behind r01 work)
    const int4   pv = ((const int4*)Pi)[row * 256 + tt];
    const float4 gv = ((const float4*)GG)[row * 256 + tt];

    // ---- r01 (redundant per block): FWHT-1024 of the two nonzero rows ----
    float w0 = BB[t] * theta[t];
    float w1 = BB[t + 1024] * theta[t + 1024];
    #pragma unroll
    for (int j = 0; j < 6; j++) {
        const float sgn = ((lane >> j) & 1) ? -1.0f : 1.0f;
        float o0 = __shfl_xor(w0, 1 << j, 64);
        float o1 = __shfl_xor(w1, 1 << j, 64);
        w0 = fmaf(sgn, w0, o0);
        w1 = fmaf(sgn, w1, o1);
    }
    float2* sr = (float2*)sB;        // 8 KB scratch (sB reused later)
    sr[t] = make_float2(w0, w1);
    __syncthreads();
    {   // bits 6-7
        const int b = t & ~192;
        const float2 q00 = sr[b], q10 = sr[b + 64], q01 = sr[b + 128], q11 = sr[b + 192];
        const float s6 = (t & 64) ? -1.0f : 1.0f;
        const float s7 = (t & 128) ? -1.0f : 1.0f;
        w0 = (q00.x + s7 * q01.x) + s6 * (q10.x + s7 * q11.x);
        w1 = (q00.y + s7 * q01.y) + s6 * (q10.y + s7 * q11.y);
    }
    __syncthreads();
    sr[t] = make_float2(w0, w1);
    // GG^2 block partial (placed here to overlap the barrier)
    float g2 = gv.x * gv.x + gv.y * gv.y + gv.z * gv.z + gv.w * gv.w;
    #pragma unroll
    for (int o = 32; o > 0; o >>= 1) g2 += __shfl_down(g2, o, 64);
    if (lane == 0) ws[t >> 6] = g2;
    __syncthreads();
    {   // bits 8-9
        const int b = t & ~768;
        const float2 q00 = sr[b], q10 = sr[b + 256], q01 = sr[b + 512], q11 = sr[b + 768];
        const float s8 = (t & 256) ? -1.0f : 1.0f;
        const float s9 = (t & 512) ? -1.0f : 1.0f;
        w0 = (q00.x + s9 * q01.x) + s8 * (q10.x + s9 * q11.x);
        w1 = (q00.y + s9 * q01.y) + s8 * (q10.y + s9 * q11.y);
    }
    r01s[t] = w0;
    r01s[1024 + t] = w1;
    __syncthreads();   // r01s ready (ws too); sr/sB free again

    // ---- gather + lo-FWHT ----
    float v[4];
    {
        int p; float g;
        p = pv.x; g = gv.x;
        v[0] = (r01s[p & 1023] + (((p >> 10) & 1) ? -1.0f : 1.0f) * r01s[1024 + (p & 1023)]) * g;
        p = pv.y; g = gv.y;
        v[1] = (r01s[p & 1023] + (((p >> 10) & 1) ? -1.0f : 1.0f) * r01s[1024 + (p & 1023)]) * g;
        p = pv.z; g = gv.z;
        v[2] = (r01s[p & 1023] + (((p >> 10) & 1) ? -1.0f : 1.0f) * r01s[1024 + (p & 1023)]) * g;
        p = pv.w; g = gv.w;
        v[3] = (r01s[p & 1023] + (((p >> 10) & 1) ? -1.0f : 1.0f) * r01s[1024 + (p & 1023)]) * g;
    }
    float a;
    a = v[0]; v[0] = a + v[1]; v[1] = a - v[1];
    a = v[2]; v[2] = a + v[3]; v[3] = a - v[3];
    a = v[0]; v[0] = a + v[2]; v[2] = a - v[2];
    a = v[1]; v[1] = a + v[3]; v[3] = a - v[3];
    #pragma unroll
    for (int j = 0; j < 6; j++) {
        const float sgn = ((lane >> j) & 1) ? -1.0f : 1.0f;
        #pragma unroll
        for (int c = 0; c < 4; c++) {
            float o = __shfl_xor(v[c], 1 << j, 64);
            v[c] = fmaf(sgn, v[c], o);
        }
    }
    {
        f32x4 vv; vv.x = v[0]; vv.y = v[1]; vv.z = v[2]; vv.w = v[3];
        sA[t] = vv;
    }
    __syncthreads();
    {
        const int b = t & ~192;
        const f32x4 q00 = sA[b];
        const f32x4 q10 = sA[b + 64];
        const f32x4 q01 = sA[b + 128];
        const f32x4 q11 = sA[b + 192];
        const float s8 = (tt & 64) ? -1.0f : 1.0f;
        const float s9 = (tt & 128) ? -1.0f : 1.0f;
        #pragma unroll
        for (int c = 0; c < 4; c++)
            v[c] = (q00[c] + s9 * q01[c]) + s8 * (q10[c] + s9 * q11[c]);
    }
    if (t == 0) {
        float s = 0;
        #pragma unroll
        for (int i = 0; i < 16; i++) s += ws[i];
        partial[blockIdx.x] = s;
    }
    {
        f32x4 vv; vv.x = v[0]; vv.y = v[1]; vv.z = v[2]; vv.w = v[3];
        *(f32x4*)&sB[s_r * 1028 + 4 * tt] = vv;
    }
    __syncthreads();
    {
        const int rl = t & 3;          // row_local
        const int lo4 = t >> 2;        // 0..255
        const f32x4 w = *(const f32x4*)&sB[rl * 1028 + lo4 * 4];
        T2[(size_t)lo4 * 1024 + blockIdx.x * 4 + rl] = w;
    }

    // ---- x-cast tail: units 0..786431 (8 floats per unit), 3 per thread ----
    {
        const f32x4* X4 = (const f32x4*)X;
        s16x8* O = (s16x8*)XB;
        size_t u = (size_t)blockIdx.x * 3072 + t;
        #pragma unroll
        for (int j = 0; j < 3; j++, u += 1024) {
            const f32x4 A4 = X4[2 * u];
            const f32x4 B4 = X4[2 * u + 1];
            union { s16x8 v; unsigned w4[4]; } o;
            o.w4[0] = cvt_pk_bf16(A4.x, A4.y);
            o.w4[1] = cvt_pk_bf16(A4.z, A4.w);
            o.w4[2] = cvt_pk_bf16(B4.x, B4.y);
            o.w4[3] = cvt_pk_bf16(B4.z, B4.w);
            O[u] = o.v;
        }
    }
}

// ---------------------------------------------------------------------------
// K4: hi-FWHT-1024 per lo-column + W_eff epilogue + {x-cast tail, 2nd half}.
// 256 blocks x 1024 threads; block g owns lo = 4g..4g+3 (one float4/thread,
// hi = t). Reads T2[g*1024 + t]: 16 KB contiguous. FWHT bits 0-5 via shfl,
// bits 6-7 and 8-9 via two LDS rounds (4-partner combine). 3 barriers total.
// ---------------------------------------------------------------------------
__global__ __launch_bounds__(1024)
void k4_fwht_hi(const f32x4* __restrict__ T2, const float* __restrict__ partial,
                const float* __restrict__ W0, ushort* __restrict__ WB,
                const float* __restrict__ X, ushort* __restrict__ XB) {
    __shared__ f32x4 sx[1024];   // 16 KB
    __shared__ float rw[17];
    const int t = threadIdx.x;
    const int g = blockIdx.x;
    const int lane = t & 63;

    float pr = 0.0f;
    if (t < 256) pr = partial[t];
    #pragma unroll
    for (int o = 32; o > 0; o >>= 1) pr += __shfl_down(pr, o, 64);
    if (t < 256 && lane == 0) rw[t >> 6] = pr;

    f32x4 vv = T2[(size_t)g * 1024 + t];
    #pragma unroll
    for (int j = 0; j < 6; j++) {
        const float sgn = ((lane >> j) & 1) ? -1.0f : 1.0f;
        #pragma unroll
        for (int c = 0; c < 4; c++) {
            float o = __shfl_xor(vv[c], 1 << j, 64);
            vv[c] = fmaf(sgn, vv[c], o);
        }
    }
    sx[t] = vv;
    __syncthreads();   // sx + rw[0..3] ready
    if (t == 0) rw[16] = rw[0] + rw[1] + rw[2] + rw[3];
    {
        const int b = t & ~192;
        const f32x4 q00 = sx[b];
        const f32x4 q10 = sx[b + 64];
        const f32x4 q01 = sx[b + 128];
        const f32x4 q11 = sx[b + 192];
        const float s6 = (t & 64) ? -1.0f : 1.0f;
        const float s7 = (t & 128) ? -1.0f : 1.0f;
        #pragma unroll
        for (int c = 0; c < 4; c++)
            vv[c] = (q00[c] + s7 * q01[c]) + s6 * (q10[c] + s7 * q11[c]);
    }
    __syncthreads();   // protect sx overwrite; publishes rw[16]
    sx[t] = vv;
    __syncthreads();
    {
        const int b = t & ~768;
        const f32x4 q00 = sx[b];
        const f32x4 q10 = sx[b + 256];
        const f32x4 q01 = sx[b + 512];
        const f32x4 q11 = sx[b + 768];
        const float s8 = (t & 256) ? -1.0f : 1.0f;
        const float s9 = (t & 512) ? -1.0f : 1.0f;
        #pragma unroll
        for (int c = 0; c < 4; c++)
            vv[c] = (q00[c] + s9 * q01[c]) + s8 * (q10[c] + s9 * q11[c]);
    }
    if (t < 768) {
        const float scale = rsqrtf(rw[16] * (float)DD);
        const size_t d = (size_t)t * 1024 + 4 * g;
        const float4 w = *(const float4*)&W0[d];
        ushort4 o;
        o.x = f2bf(w.x + vv.x * scale);
        o.y = f2bf(w.y + vv.y * scale);
        o.z = f2bf(w.z + vv.z * scale);
        o.w = f2bf(w.w + vv.w * scale);
        *(ushort4*)&WB[d] = o;
    }

    // ---- x-cast tail: units 786432..1572863, 3 per thread ----
    {
        const f32x4* X4 = (const f32x4*)X;
        s16x8* O = (s16x8*)XB;
        size_t u = 786432 + (size_t)g * 3072 + t;
        #pragma unroll
        for (int j = 0; j < 3; j++, u += 1024) {
            const f32x4 A4 = X4[2 * u];
            const f32x4 B4 = X4[2 * u + 1];
            union { s16x8 v; unsigned w4[4]; } o;
            o.w4[0] = cvt_pk_bf16(A4.x, A4.y);
            o.w4[1] = cvt_pk_bf16(A4.z, A4.w);
            o.w4[2] = cvt_pk_bf16(B4.x, B4.y);
            o.w4[3] = cvt_pk_bf16(B4.z, B4.w);
            O[u] = o.v;
        }
    }
}

// ---------------------------------------------------------------------------
// K7: GEMM  C[m][n] = sum_k A[m][k]*B[n][k] + bias[n]   (R10-verified form)
// A: MROWS x 768 bf16 (XB), B: 1024 x 768 bf16 (W_eff), C: f32.
// m-major grid dim3(128,8); FETCH 30.8 MB (die-level L3 serves A reuse).
// 128x128 tile, BK=64, 4 waves (2x2), 2x2 MFMA 32x32x16 per wave, 4 k-steps.
// Double-buffered (T3 minimum): stage t+1 before compute t, 1 barrier/iter.
// XOR-swizzled LDS (128B row pitch REQUIRED: 64B pitch collides 8-way, R12):
//   16B slot s <-> row = s>>3, kc = (s&7) ^ (row&7).
// C/D: col = lane&31, row = (reg&3) + 8*(reg>>2) + 4*(lane>>5)  [m74/m101].
// ---------------------------------------------------------------------------
#define BM 128
#define BN 128
#define BK 64
#define KITERS (INF / BK)   // 12

__global__ __launch_bounds__(256)
void k7_gemm(const ushort* __restrict__ A, const ushort* __restrict__ B,
             const float* __restrict__ bias, float* __restrict__ C) {
    __shared__ ushort As[2][BM * BK];   // 2 x 16 KB
    __shared__ ushort Bs[2][BN * BK];   // 2 x 16 KB
    const int tid  = threadIdx.x;
    const int lane = tid & 63;
    const int wave = tid >> 6;
    const int m0 = blockIdx.x * BM;
    const int n0 = blockIdx.y * BN;
    const int wm = (wave & 1) * 64;
    const int wn = (wave >> 1) * 64;

    const int fr_row = lane & 31;     // row within 32-tile
    const int fr_kh  = lane >> 5;     // k-half 0..1 (8 k each)

    f32x16 acc[2][2];
    #pragma unroll
    for (int i = 0; i < 2; i++)
        #pragma unroll
        for (int j = 0; j < 2; j++) acc[i][j] = (f32x16)(0.0f);

    // stage k-tile kt into buffer bsel (8 global_load_lds, 16B each)
    auto stage = [&](int bsel, int kt) {
        #pragma unroll
        for (int i = 0; i < 4; i++) {
            const int s   = i * 256 + tid;       // LDS slot (16B units)
            const int row = s >> 3;
            const int kc  = (s & 7) ^ (row & 7);
            const ushort* ga = A + (size_t)(m0 + row) * INF + kt + kc * 8;
            const ushort* gb = B + (size_t)(n0 + row) * INF + kt + kc * 8;
            __builtin_amdgcn_global_load_lds(
                (const __attribute__((address_space(1))) void*)ga,
                (__attribute__((address_space(3))) void*)&As[bsel][i * 2048 + wave * 512], 16, 0, 0);
            __builtin_amdgcn_global_load_lds(
                (const __attribute__((address_space(1))) void*)gb,
                (__attribute__((address_space(3))) void*)&Bs[bsel][i * 2048 + wave * 512], 16, 0, 0);
        }
    };

    stage(0, 0);
    __syncthreads();                     // drains vmcnt(0): tile 0 ready

    for (int t = 0; t < KITERS; t++) {
        const int cur = t & 1;
        if (t + 1 < KITERS) stage(cur ^ 1, (t + 1) * BK);   // prefetch next tile

        // --- fragments + MFMA, four 16-k steps, from buf[cur] ---
        const ushort* Ab = As[cur];
        const ushort* Bb = Bs[cur];
        #pragma unroll
        for (int ks = 0; ks < 4; ks++) {
            const int kc = ks * 2 + fr_kh;       // 8-ushort unit within BK
            s16x8 af[2], bf[2];
            #pragma unroll
            for (int mi = 0; mi < 2; mi++) {
                const int r = wm + mi * 32 + fr_row;
                af[mi] = *(const s16x8*)&Ab[(r * 8 + (kc ^ (r & 7))) * 8];
            }
            #pragma unroll
            for (int ni = 0; ni < 2; ni++) {
                const int r = wn + ni * 32 + fr_row;
                bf[ni] = *(const s16x8*)&Bb[(r * 8 + (kc ^ (r & 7))) * 8];
            }
            #pragma unroll
            for (int mi = 0; mi < 2; mi++)
                #pragma unroll
                for (int ni = 0; ni < 2; ni++)
                    acc[mi][ni] = __builtin_amdgcn_mfma_f32_32x32x16_bf16(
                        af[mi], bf[ni], acc[mi][ni], 0, 0, 0);
        }
        // barrier: (a) all waves done reading buf[cur] -> next iter may
        // overwrite it; (b) auto vmcnt(0) drain -> prefetched tile ready.
        __syncthreads();
    }

    // --- epilogue: C/D col=lane&31, row=(reg&3)+8*(reg>>2)+4*(lane>>5) ---
    const int ccol = lane & 31;
    const int rbase = (lane >> 5) * 4;
    #pragma unroll
    for (int ni = 0; ni < 2; ni++) {
        const int n = n0 + wn + ni * 32 + ccol;
        const float bv = bias[n];
        #pragma unroll
        for (int mi = 0; mi < 2; mi++) {
            const int mb = m0 + wm + mi * 32 + rbase;
            #pragma unroll
            for (int r = 0; r < 16; r++) {
                const int m = mb + (r & 3) + 8 * (r >> 2);
                C[(size_t)m * OUTF + n] = acc[mi][ni][r] + bv;
            }
        }
    }
}

// ---------------------------------------------------------------------------
extern "C" void kernel_launch(void* const* d_in, const int* in_sizes, int n_in,
                              void* d_out, int out_size, void* d_ws, size_t ws_size,
                              hipStream_t stream) {
    (void)in_sizes; (void)n_in; (void)out_size; (void)ws_size;
    const float* x     = (const float*)d_in[0];
    const float* theta = (const float*)d_in[1];
    const float* W0    = (const float*)d_in[2];
    const float* bias  = (const float*)d_in[3];
    const float* BB    = (const float*)d_in[4];
    const float* GG    = (const float*)d_in[5];
    const int*   Pi    = (const int*)d_in[6];      // int64 inputs arrive as int32
    float* out = (float*)d_out;

    char* ws = (char*)d_ws;
    ushort* XB   = (ushort*)ws;                      // 16384*768 bf16 = 25165824 B
    f32x4*  T2   = (f32x4*)(ws + 25165824);          // LL f32 = 4194304 B
    ushort* WB   = (ushort*)(ws + 29360128);         // 1024*768 bf16 = 1572864 B
    float*  PART = (float*)(ws + 30932992);          // 256 f32 partials

    k3_gather_fwht_lo<<<256, 1024, 0, stream>>>(Pi, GG, BB, theta, x, XB, T2, PART);
    k4_fwht_hi      <<<256, 1024, 0, stream>>>(T2, PART, W0, WB, x, XB);
    k7_gemm<<<dim3(MROWS/BM, OUTF/BN), 256, 0, stream>>>(XB, WB, bias, out);
}

// Round 7
// 159.681 us; speedup vs baseline: 1.1636x; 1.0151x over previous
//
#include <hip/hip_runtime.h>
#include <hip/hip_bf16.h>

// ---------------------------------------------------------------------------
// GlobalIntrinsicLinear: Fastfood update + GEMM
//   LL = 1<<20, DD = 1024*768, OUT=1024, IN=768, M = 8*2048 = 16384
// Inputs: x(8,2048,768) f32, theta(2048) f32, W_0(1024,768) f32, b(1024) f32,
//         BB(LL) f32, GG(LL) f32, Pi(LL) int32 (harness narrows int64)
// Output: (8,2048,1024) f32
//
// R14: k7 -> 256x256 8-wave phase-split schedule (T3 port, conservative):
//   - 512 thr (2M x 4N waves), per-wave 128x64 out (acc[4][2] of 32x32).
//   - Per K-tile 4 phases: phase p = {4 ds_read A-frags(mi=p)} -> setprio(1)
//     -> 8 MFMA -> setprio(0) -> raw s_barrier (hazard-free: phases are
//     read-only on the live buffer). B-frags read once at p=0, held in regs.
//     MFMA:ds_read 1.33 vs 1.0.
//   - Stage of tile t+1 burst-issued at phases 0-1 (early-issue, ~3 phases
//     of cover); single __syncthreads() per K-tile boundary = the only
//     vmcnt drain (no manual vmcnt counting -> no race surface).
//   - Grid 64x4 = 256 blocks = 1/CU; LDS 128 KB; same proven swizzle,
//     fragment and C/D layouts -> bit-identical numerics.
//   k3/k4 = R12/R13 folded side-chain (unchanged, ~13us, BW-floor).
// ---------------------------------------------------------------------------

#define LL (1 << 20)
#define DD (1024 * 768)
#define OUTF 1024
#define INF 768
#define MROWS 16384

typedef __attribute__((ext_vector_type(8))) short s16x8;
typedef __attribute__((ext_vector_type(4))) float f32x4;
typedef __attribute__((ext_vector_type(16))) float f32x16;

__device__ __forceinline__ unsigned short f2bf(float f) {
    union { float f; unsigned u; } v; v.f = f;
    unsigned r = v.u + 0x7FFF + ((v.u >> 16) & 1);   // RNE
    return (unsigned short)(r >> 16);
}

// packed f32->bf16 RNE; no builtin on gfx950 (m240)
__device__ __forceinline__ unsigned cvt_pk_bf16(float lo, float hi) {
    unsigned r;
    asm("v_cvt_pk_bf16_f32 %0, %1, %2" : "=v"(r) : "v"(lo), "v"(hi));
    return r;
}

// ---------------------------------------------------------------------------
// K3: {in-block r01 FWHT} + gather (Pi,GG) + lo-FWHT-1024 per hi-row + GG^2
// partials + {x-cast tail, first half}. 256 blocks x 1024 threads.
// ---------------------------------------------------------------------------
__global__ __launch_bounds__(1024)
void k3_gather_fwht_lo(const int* __restrict__ Pi, const float* __restrict__ GG,
                       const float* __restrict__ BB, const float* __restrict__ theta,
                       const float* __restrict__ X, ushort* __restrict__ XB,
                       f32x4* __restrict__ T2, float* __restrict__ partial) {
    __shared__ float r01s[2048];
    __shared__ f32x4 sA[1024];       // 16 KB
    __shared__ float sB[4 * 1028];   // 16.4 KB (pitch 1028 breaks conflicts)
    __shared__ float ws[16];
    const int t = threadIdx.x;
    const int s_r = t >> 8, tt = t & 255, lane = t & 63;
    const int row = blockIdx.x * 4 + s_r;

    // gather operands early (latency hidden behind r01 work)
    const int4   pv = ((const int4*)Pi)[row * 256 + tt];
    const float4 gv = ((const float4*)GG)[row * 256 + tt];

    // ---- r01 (redundant per block): FWHT-1024 of the two nonzero rows ----
    float w0 = BB[t] * theta[t];
    float w1 = BB[t + 1024] * theta[t + 1024];
    #pragma unroll
    for (int j = 0; j < 6; j++) {
        const float sgn = ((lane >> j) & 1) ? -1.0f : 1.0f;
        float o0 = __shfl_xor(w0, 1 << j, 64);
        float o1 = __shfl_xor(w1, 1 << j, 64);
        w0 = fmaf(sgn, w0, o0);
        w1 = fmaf(sgn, w1, o1);
    }
    float2* sr = (float2*)sB;        // 8 KB scratch (sB reused later)
    sr[t] = make_float2(w0, w1);
    __syncthreads();
    {   // bits 6-7
        const int b = t & ~192;
        const float2 q00 = sr[b], q10 = sr[b + 64], q01 = sr[b + 128], q11 = sr[b + 192];
        const float s6 = (t & 64) ? -1.0f : 1.0f;
        const float s7 = (t & 128) ? -1.0f : 1.0f;
        w0 = (q00.x + s7 * q01.x) + s6 * (q10.x + s7 * q11.x);
        w1 = (q00.y + s7 * q01.y) + s6 * (q10.y + s7 * q11.y);
    }
    __syncthreads();
    sr[t] = make_float2(w0, w1);
    // GG^2 block partial (placed here to overlap the barrier)
    float g2 = gv.x * gv.x + gv.y * gv.y + gv.z * gv.z + gv.w * gv.w;
    #pragma unroll
    for (int o = 32; o > 0; o >>= 1) g2 += __shfl_down(g2, o, 64);
    if (lane == 0) ws[t >> 6] = g2;
    __syncthreads();
    {   // bits 8-9
        const int b = t & ~768;
        const float2 q00 = sr[b], q10 = sr[b + 256], q01 = sr[b + 512], q11 = sr[b + 768];
        const float s8 = (t & 256) ? -1.0f : 1.0f;
        const float s9 = (t & 512) ? -1.0f : 1.0f;
        w0 = (q00.x + s9 * q01.x) + s8 * (q10.x + s9 * q11.x);
        w1 = (q00.y + s9 * q01.y) + s8 * (q10.y + s9 * q11.y);
    }
    r01s[t] = w0;
    r01s[1024 + t] = w1;
    __syncthreads();   // r01s ready (ws too); sr/sB free again

    // ---- gather + lo-FWHT ----
    float v[4];
    {
        int p; float g;
        p = pv.x; g = gv.x;
        v[0] = (r01s[p & 1023] + (((p >> 10) & 1) ? -1.0f : 1.0f) * r01s[1024 + (p & 1023)]) * g;
        p = pv.y; g = gv.y;
        v[1] = (r01s[p & 1023] + (((p >> 10) & 1) ? -1.0f : 1.0f) * r01s[1024 + (p & 1023)]) * g;
        p = pv.z; g = gv.z;
        v[2] = (r01s[p & 1023] + (((p >> 10) & 1) ? -1.0f : 1.0f) * r01s[1024 + (p & 1023)]) * g;
        p = pv.w; g = gv.w;
        v[3] = (r01s[p & 1023] + (((p >> 10) & 1) ? -1.0f : 1.0f) * r01s[1024 + (p & 1023)]) * g;
    }
    float a;
    a = v[0]; v[0] = a + v[1]; v[1] = a - v[1];
    a = v[2]; v[2] = a + v[3]; v[3] = a - v[3];
    a = v[0]; v[0] = a + v[2]; v[2] = a - v[2];
    a = v[1]; v[1] = a + v[3]; v[3] = a - v[3];
    #pragma unroll
    for (int j = 0; j < 6; j++) {
        const float sgn = ((lane >> j) & 1) ? -1.0f : 1.0f;
        #pragma unroll
        for (int c = 0; c < 4; c++) {
            float o = __shfl_xor(v[c], 1 << j, 64);
            v[c] = fmaf(sgn, v[c], o);
        }
    }
    {
        f32x4 vv; vv.x = v[0]; vv.y = v[1]; vv.z = v[2]; vv.w = v[3];
        sA[t] = vv;
    }
    __syncthreads();
    {
        const int b = t & ~192;
        const f32x4 q00 = sA[b];
        const f32x4 q10 = sA[b + 64];
        const f32x4 q01 = sA[b + 128];
        const f32x4 q11 = sA[b + 192];
        const float s8 = (tt & 64) ? -1.0f : 1.0f;
        const float s9 = (tt & 128) ? -1.0f : 1.0f;
        #pragma unroll
        for (int c = 0; c < 4; c++)
            v[c] = (q00[c] + s9 * q01[c]) + s8 * (q10[c] + s9 * q11[c]);
    }
    if (t == 0) {
        float s = 0;
        #pragma unroll
        for (int i = 0; i < 16; i++) s += ws[i];
        partial[blockIdx.x] = s;
    }
    {
        f32x4 vv; vv.x = v[0]; vv.y = v[1]; vv.z = v[2]; vv.w = v[3];
        *(f32x4*)&sB[s_r * 1028 + 4 * tt] = vv;
    }
    __syncthreads();
    {
        const int rl = t & 3;          // row_local
        const int lo4 = t >> 2;        // 0..255
        const f32x4 w = *(const f32x4*)&sB[rl * 1028 + lo4 * 4];
        T2[(size_t)lo4 * 1024 + blockIdx.x * 4 + rl] = w;
    }

    // ---- x-cast tail: units 0..786431 (8 floats per unit), 3 per thread ----
    {
        const f32x4* X4 = (const f32x4*)X;
        s16x8* O = (s16x8*)XB;
        size_t u = (size_t)blockIdx.x * 3072 + t;
        #pragma unroll
        for (int j = 0; j < 3; j++, u += 1024) {
            const f32x4 A4 = X4[2 * u];
            const f32x4 B4 = X4[2 * u + 1];
            union { s16x8 v; unsigned w4[4]; } o;
            o.w4[0] = cvt_pk_bf16(A4.x, A4.y);
            o.w4[1] = cvt_pk_bf16(A4.z, A4.w);
            o.w4[2] = cvt_pk_bf16(B4.x, B4.y);
            o.w4[3] = cvt_pk_bf16(B4.z, B4.w);
            O[u] = o.v;
        }
    }
}

// ---------------------------------------------------------------------------
// K4: hi-FWHT-1024 per lo-column + W_eff epilogue + {x-cast tail, 2nd half}.
// ---------------------------------------------------------------------------
__global__ __launch_bounds__(1024)
void k4_fwht_hi(const f32x4* __restrict__ T2, const float* __restrict__ partial,
                const float* __restrict__ W0, ushort* __restrict__ WB,
                const float* __restrict__ X, ushort* __restrict__ XB) {
    __shared__ f32x4 sx[1024];   // 16 KB
    __shared__ float rw[17];
    const int t = threadIdx.x;
    const int g = blockIdx.x;
    const int lane = t & 63;

    float pr = 0.0f;
    if (t < 256) pr = partial[t];
    #pragma unroll
    for (int o = 32; o > 0; o >>= 1) pr += __shfl_down(pr, o, 64);
    if (t < 256 && lane == 0) rw[t >> 6] = pr;

    f32x4 vv = T2[(size_t)g * 1024 + t];
    #pragma unroll
    for (int j = 0; j < 6; j++) {
        const float sgn = ((lane >> j) & 1) ? -1.0f : 1.0f;
        #pragma unroll
        for (int c = 0; c < 4; c++) {
            float o = __shfl_xor(vv[c], 1 << j, 64);
            vv[c] = fmaf(sgn, vv[c], o);
        }
    }
    sx[t] = vv;
    __syncthreads();   // sx + rw[0..3] ready
    if (t == 0) rw[16] = rw[0] + rw[1] + rw[2] + rw[3];
    {
        const int b = t & ~192;
        const f32x4 q00 = sx[b];
        const f32x4 q10 = sx[b + 64];
        const f32x4 q01 = sx[b + 128];
        const f32x4 q11 = sx[b + 192];
        const float s6 = (t & 64) ? -1.0f : 1.0f;
        const float s7 = (t & 128) ? -1.0f : 1.0f;
        #pragma unroll
        for (int c = 0; c < 4; c++)
            vv[c] = (q00[c] + s7 * q01[c]) + s6 * (q10[c] + s7 * q11[c]);
    }
    __syncthreads();   // protect sx overwrite; publishes rw[16]
    sx[t] = vv;
    __syncthreads();
    {
        const int b = t & ~768;
        const f32x4 q00 = sx[b];
        const f32x4 q10 = sx[b + 256];
        const f32x4 q01 = sx[b + 512];
        const f32x4 q11 = sx[b + 768];
        const float s8 = (t & 256) ? -1.0f : 1.0f;
        const float s9 = (t & 512) ? -1.0f : 1.0f;
        #pragma unroll
        for (int c = 0; c < 4; c++)
            vv[c] = (q00[c] + s9 * q01[c]) + s8 * (q10[c] + s9 * q11[c]);
    }
    if (t < 768) {
        const float scale = rsqrtf(rw[16] * (float)DD);
        const size_t d = (size_t)t * 1024 + 4 * g;
        const float4 w = *(const float4*)&W0[d];
        ushort4 o;
        o.x = f2bf(w.x + vv.x * scale);
        o.y = f2bf(w.y + vv.y * scale);
        o.z = f2bf(w.z + vv.z * scale);
        o.w = f2bf(w.w + vv.w * scale);
        *(ushort4*)&WB[d] = o;
    }

    // ---- x-cast tail: units 786432..1572863, 3 per thread ----
    {
        const f32x4* X4 = (const f32x4*)X;
        s16x8* O = (s16x8*)XB;
        size_t u = 786432 + (size_t)g * 3072 + t;
        #pragma unroll
        for (int j = 0; j < 3; j++, u += 1024) {
            const f32x4 A4 = X4[2 * u];
            const f32x4 B4 = X4[2 * u + 1];
            union { s16x8 v; unsigned w4[4]; } o;
            o.w4[0] = cvt_pk_bf16(A4.x, A4.y);
            o.w4[1] = cvt_pk_bf16(A4.z, A4.w);
            o.w4[2] = cvt_pk_bf16(B4.x, B4.y);
            o.w4[3] = cvt_pk_bf16(B4.z, B4.w);
            O[u] = o.v;
        }
    }
}

// ---------------------------------------------------------------------------
// K7: GEMM  C[m][n] = sum_k A[m][k]*B[n][k] + bias[n]
// A: MROWS x 768 bf16 (XB), B: 1024 x 768 bf16 (W_eff), C: f32.
// 256x256 tile, BK=64, 512 threads = 8 waves (2M x 4N); per-wave 128x64 out
// = acc[4][2] 32x32 tiles. Grid dim3(64,4) m-major, 1 block/CU.
// Per K-tile, 4 phases: phase p reads A-frags mi=p (4 ds_read; B-frags read
// once at p=0, held in regs: MFMA:ds_read = 32:24), setprio-wrapped 8 MFMA,
// raw s_barrier between phases (read-only on live buffer -> hazard-free).
// Stage of tile t+1 burst-issued at phases 0-1 into the other buffer
// (early-issue: ~3 phases of latency cover); one __syncthreads() per K-tile
// boundary is the only vmcnt drain (correct by construction).
// XOR-swizzled LDS (128B row pitch): 16B slot s <-> row=s>>3, kc=(s&7)^(row&7).
// C/D: col = lane&31, row = (reg&3) + 8*(reg>>2) + 4*(lane>>5)  [m74/m101].
// ---------------------------------------------------------------------------
#define BM 256
#define BN 256
#define BK 64
#define KTILES (INF / BK)   // 12

__global__ __launch_bounds__(512)
void k7_gemm(const ushort* __restrict__ A, const ushort* __restrict__ B,
             const float* __restrict__ bias, float* __restrict__ C) {
    __shared__ ushort As[2][BM * BK];   // 2 x 32 KB
    __shared__ ushort Bs[2][BN * BK];   // 2 x 32 KB
    const int tid  = threadIdx.x;
    const int lane = tid & 63;
    const int wave = tid >> 6;          // 0..7
    const int wr   = wave >> 2;         // 0..1: row half (128 rows)
    const int wc   = wave & 3;          // 0..3: col quarter (64 cols)
    const int m0 = blockIdx.x * BM;
    const int n0 = blockIdx.y * BN;

    const int fr_row = lane & 31;       // row within 32-tile
    const int fr_kh  = lane >> 5;       // k-half 0..1 (8 k each)

    f32x16 acc[4][2];
    #pragma unroll
    for (int i = 0; i < 4; i++)
        #pragma unroll
        for (int j = 0; j < 2; j++) acc[i][j] = (f32x16)(0.0f);

    // stage half h (0/1 = rows h*128..h*128+127) of one matrix k-tile into Ls.
    // 2 global_load_lds x 16B per thread; swizzle in SOURCE addr, linear dest.
    auto stage_half = [&](ushort* Ls, const ushort* G, int grow0, int kt, int h) {
        #pragma unroll
        for (int j = 0; j < 2; j++) {
            const int s   = h * 1024 + j * 512 + tid;      // slot 0..2047 (16B)
            const int row = s >> 3;
            const int kc  = (s & 7) ^ (row & 7);
            const ushort* g = G + (size_t)(grow0 + row) * INF + kt * BK + kc * 8;
            __builtin_amdgcn_global_load_lds(
                (const __attribute__((address_space(1))) void*)g,
                (__attribute__((address_space(3))) void*)
                    &Ls[(h * 1024 + j * 512 + wave * 64) * 8], 16, 0, 0);
        }
    };

    // prologue: tile 0 -> buf0
    stage_half(As[0], A, m0, 0, 0);
    stage_half(As[0], A, m0, 0, 1);
    stage_half(Bs[0], B, n0, 0, 0);
    stage_half(Bs[0], B, n0, 0, 1);
    __syncthreads();                     // vmcnt(0) drain: tile 0 ready

    for (int t = 0; t < KTILES; t++) {
        const int cur = t & 1;
        const ushort* Ab = As[cur];
        const ushort* Bb = Bs[cur];
        ushort* An = As[cur ^ 1];
        ushort* Bn = Bs[cur ^ 1];
        const bool pf = (t + 1 < KTILES);

        s16x8 bfr[2][4];                 // B-frags held for the whole K-tile
        #pragma unroll
        for (int p = 0; p < 4; p++) {
            if (p == 0) {
                #pragma unroll
                for (int ni = 0; ni < 2; ni++) {
                    const int r = wc * 64 + ni * 32 + fr_row;
                    #pragma unroll
                    for (int ks = 0; ks < 4; ks++) {
                        const int kc = ks * 2 + fr_kh;
                        bfr[ni][ks] = *(const s16x8*)&Bb[(r * 8 + (kc ^ (r & 7))) * 8];
                    }
                }
            }
            s16x8 af[4];
            {
                const int r = wr * 128 + p * 32 + fr_row;
                #pragma unroll
                for (int ks = 0; ks < 4; ks++) {
                    const int kc = ks * 2 + fr_kh;
                    af[ks] = *(const s16x8*)&Ab[(r * 8 + (kc ^ (r & 7))) * 8];
                }
            }
            // burst-early staging of tile t+1 (phases 0-1 only)
            if (pf) {
                if (p == 0) {
                    stage_half(An, A, m0, t + 1, 0);
                    stage_half(An, A, m0, t + 1, 1);
                } else if (p == 1) {
                    stage_half(Bn, B, n0, t + 1, 0);
                    stage_half(Bn, B, n0, t + 1, 1);
                }
            }
            __builtin_amdgcn_s_setprio(1);
            #pragma unroll
            for (int ks = 0; ks < 4; ks++) {
                acc[p][0] = __builtin_amdgcn_mfma_f32_32x32x16_bf16(
                    af[ks], bfr[0][ks], acc[p][0], 0, 0, 0);
                acc[p][1] = __builtin_amdgcn_mfma_f32_32x32x16_bf16(
                    af[ks], bfr[1][ks], acc[p][1], 0, 0, 0);
            }
            __builtin_amdgcn_s_setprio(0);
            if (p < 3) __builtin_amdgcn_s_barrier();   // phase fence (no hazard)
        }
        // tile boundary: all waves done with buf[cur]; vmcnt(0)+lgkm drain
        // completes tile t+1's staged loads.
        __syncthreads();
    }

    // --- epilogue: C/D col=lane&31, row=(reg&3)+8*(reg>>2)+4*(lane>>5) ---
    const int ccol = lane & 31;
    const int rbase = (lane >> 5) * 4;
    #pragma unroll
    for (int ni = 0; ni < 2; ni++) {
        const int n = n0 + wc * 64 + ni * 32 + ccol;
        const float bv = bias[n];
        #pragma unroll
        for (int mi = 0; mi < 4; mi++) {
            const int mb = m0 + wr * 128 + mi * 32 + rbase;
            #pragma unroll
            for (int r = 0; r < 16; r++) {
                const int m = mb + (r & 3) + 8 * (r >> 2);
                C[(size_t)m * OUTF + n] = acc[mi][ni][r] + bv;
            }
        }
    }
}

// ---------------------------------------------------------------------------
extern "C" void kernel_launch(void* const* d_in, const int* in_sizes, int n_in,
                              void* d_out, int out_size, void* d_ws, size_t ws_size,
                              hipStream_t stream) {
    (void)in_sizes; (void)n_in; (void)out_size; (void)ws_size;
    const float* x     = (const float*)d_in[0];
    const float* theta = (const float*)d_in[1];
    const float* W0    = (const float*)d_in[2];
    const float* bias  = (const float*)d_in[3];
    const float* BB    = (const float*)d_in[4];
    const float* GG    = (const float*)d_in[5];
    const int*   Pi    = (const int*)d_in[6];      // int64 inputs arrive as int32
    float* out = (float*)d_out;

    char* ws = (char*)d_ws;
    ushort* XB   = (ushort*)ws;                      // 16384*768 bf16 = 25165824 B
    f32x4*  T2   = (f32x4*)(ws + 25165824);          // LL f32 = 4194304 B
    ushort* WB   = (ushort*)(ws + 29360128);         // 1024*768 bf16 = 1572864 B
    float*  PART = (float*)(ws + 30932992);          // 256 f32 partials

    k3_gather_fwht_lo<<<256, 1024, 0, stream>>>(Pi, GG, BB, theta, x, XB, T2, PART);
    k4_fwht_hi      <<<256, 1024, 0, stream>>>(T2, PART, W0, WB, x, XB);
    k7_gemm<<<dim3(MROWS/BM, OUTF/BN), 512, 0, stream>>>(XB, WB, bias, out);
}